// Round 13
// baseline (241.697 us; speedup 1.0000x reference)
//
#include <hip/hip_runtime.h>
#include <hip/hip_bf16.h>

typedef unsigned short u16;
typedef unsigned int   u32;
typedef __attribute__((ext_vector_type(8))) short s16x8;
typedef __attribute__((ext_vector_type(16))) float f32x16;

#define BN_EPS 1e-3f
// problem dims
#define NB 16
#define NC 64
#define NH 160
#define NW 160
#define HP 162   // padded H
#define WPD 162  // padded W

// workspace layout (bytes)
#define OFF_XT 0UL
#define SZ_XT  (16UL*162*162*64*2)     // 53,747,712  padded NHWC bf16
#define OFF_WT (OFF_XT + SZ_XT)
#define SZ_WT  (4UL*64*9*64*2)         // 294,912  [e][ch][pos][cio][co][8ci] bf16
#define OFF_SH (OFF_WT + SZ_WT)        // bn shift [4][64] f32
#define OFF_G  (OFF_SH + 1024UL)       // g [16][64] f32
#define OFF_WE (OFF_G + 4096UL)        // wexp [16][4] f32
#define OFF_CT (OFF_WE + 256UL)        // steal counters u32[8] (+pad)
#define OFF_GP (OFF_CT + 256UL)        // gpart [1024][800] f32 (3.28 MB)

// conv_main LDS partition (dynamic, 81,680 B total -> 2 blocks/CU)
#define XSTRIDE 342
#define XLS_BYTES (8 * XSTRIDE * 16)   // 43,776
#define WLS_BYTES (2304 * 16)          // 36,864 = 36 k-octet rows x 64 co x 16 B
#define SHLS_BYTES 1024                // shift [4][64] f32 in LDS
#define SMEM_TOTAL (XLS_BYTES + WLS_BYTES + SHLS_BYTES + 16)

__device__ __forceinline__ u16 f2bf(float f) {
    u32 u = __builtin_bit_cast(u32, f);
    u += 0x7fffu + ((u >> 16) & 1u);   // round-to-nearest-even
    return (u16)(u >> 16);
}

// ---- weights -> [e][ch][pos][cio][co][8ci] bf16, dx-major, BN-scale folded
__global__ void prep_w(const float* __restrict__ cw, u16* __restrict__ wt,
                       const float* __restrict__ gamma, const float* __restrict__ beta,
                       const float* __restrict__ mean, const float* __restrict__ var,
                       float* __restrict__ shift) {
    int idx = blockIdx.x * 256 + threadIdx.x;
    if (idx < 4 * 2 * 9 * 4 * 64 * 8) {
        int cin = idx & 7;
        int t = idx >> 3;
        int co = t & 63; t >>= 6;
        int cio = t & 3; t >>= 2;
        int pos = t % 9; t /= 9;
        int ch = t & 1;
        int e = t >> 1;
        int tsp = (pos % 3) * 3 + (pos / 3);   // spatial tap dy*3+dx
        int ci = ch * 32 + cio * 8 + cin;
        int ec = e * 64 + co;
        float sc = gamma[ec] * rsqrtf(var[ec] + BN_EPS);
        wt[idx] = f2bf(cw[(((long)ec) * 64 + ci) * 9 + tsp] * sc);
    }
    if (idx < 256) {
        float sc = gamma[idx] * rsqrtf(var[idx] + BN_EPS);
        shift[idx] = beta[idx] - mean[idx] * sc;
    }
}

// ---- x NCHW f32 -> padded NHWC bf16 + router partials + border zero ------
__global__ void prep_x(const float* __restrict__ x, u16* __restrict__ xt,
                       float* __restrict__ gpart) {
    __shared__ float tile[64][33];
    int blk = blockIdx.x;
    int t = threadIdx.x;
    if (blk >= 12800) {                // zero the 1-px halo border
        int bb = blk - 12800;          // 0..2591 = b*162 + hp
        int hp = bb % 162, b = bb / 162;
        u32* row = (u32*)xt + (((long)b * 162 + hp) * 162) * 32;
        if (hp == 0 || hp == 161) {
            for (int i = t; i < 162 * 32; i += 256) row[i] = 0u;
        } else if (t < 64) {
            int p = (t >> 5) ? 161 : 0;
            row[p * 32 + (t & 31)] = 0u;
        }
        return;
    }
    int wt5 = blk % 5;
    int tmp = blk / 5;
    int h = tmp % 160, b = tmp / 160;
    int w0 = wt5 * 32;
    int w = t & 31, c0 = t >> 5;       // c0 in 0..7
#pragma unroll
    for (int i = 0; i < 8; ++i) {
        int c = c0 + 8 * i;
        tile[c][w] = x[(((long)b * 64 + c) * 160 + h) * 160 + w0 + w];
    }
    __syncthreads();
    if (t < 64) {                      // per-channel partial sum over 32 w
        float s = 0.f;
#pragma unroll
        for (int wi = 0; wi < 32; ++wi) s += tile[t][wi];
        gpart[((long)(b * 64 + t)) * 800 + h * 5 + wt5] = s;
    }
    u32* xt32 = (u32*)xt;
    long base = ((((long)b * 162 + h + 1) * 162) + (w0 + 1)) * 32; // u32 index
#pragma unroll
    for (int j = 0; j < 4; ++j) {
        int idx = t + 256 * j;         // 0..1023
        int p = idx >> 5, cp = idx & 31;
        float v0 = tile[2 * cp][p], v1 = tile[2 * cp + 1][p];
        xt32[base + p * 32 + cp] = (u32)f2bf(v0) | ((u32)f2bf(v1) << 16);
    }
}

// ---- finish global average pool (1024 blocks: parallel) ------------------
__global__ void g_reduce(const float* __restrict__ gpart, float* __restrict__ g) {
    int id = blockIdx.x;               // 1024 = b*64+c
    int t = threadIdx.x;
    float s = 0.f;
    for (int i = t; i < 800; i += 256) s += gpart[(long)id * 800 + i];
#pragma unroll
    for (int off = 32; off > 0; off >>= 1) s += __shfl_down(s, off, 64);
    __shared__ float red[4];
    if ((t & 63) == 0) red[t >> 6] = s;
    __syncthreads();
    if (t == 0) g[id] = (red[0] + red[1] + red[2] + red[3]) * (1.f / 25600.f);
}

// ---- router: fc1 -> relu -> fc2 -> softmax -------------------------------
__global__ void router(const float* __restrict__ g, const float* __restrict__ fc1w,
                       const float* __restrict__ fc2w, const float* __restrict__ fc2b,
                       float* __restrict__ wexp) {
    __shared__ float gL[16][64];
    __shared__ float h1[16][16];
    __shared__ float z[16][4];
    int t = threadIdx.x;
    for (int i = t; i < 1024; i += 256) gL[i >> 6][i & 63] = g[i];
    __syncthreads();
    {
        int b = t >> 4, r = t & 15;
        float s = 0.f;
#pragma unroll
        for (int c = 0; c < 64; ++c) s += gL[b][c] * fc1w[r * 64 + c];
        h1[b][r] = fmaxf(s, 0.f);
    }
    __syncthreads();
    if (t < 64) {
        int b = t >> 2, e = t & 3;
        float s = fc2b[e];
#pragma unroll
        for (int r = 0; r < 16; ++r) s += h1[b][r] * fc2w[e * 16 + r];
        z[b][e] = s;
    }
    __syncthreads();
    if (t < 16) {
        int b = t;
        float m = fmaxf(fmaxf(z[b][0], z[b][1]), fmaxf(z[b][2], z[b][3]));
        float e0 = __expf(z[b][0] - m), e1 = __expf(z[b][1] - m);
        float e2 = __expf(z[b][2] - m), e3 = __expf(z[b][3] - m);
        float inv = 1.f / (e0 + e1 + e2 + e3);
        wexp[b * 4 + 0] = e0 * inv; wexp[b * 4 + 1] = e1 * inv;
        wexp[b * 4 + 2] = e2 * inv; wexp[b * 4 + 3] = e3 * inv;
    }
}

// ---- main: persistent-block work-stealing implicit-GEMM conv -------------
// grid 512 (2/CU exactly); each block steals 256-px tiles from per-XCD
// counters (own range first -> keeps batch-contiguous L2 write combining).
// Per tile: R12's 8-stage pipeline (3-phase counted vmcnt, dx-grouped
// B-reuse, BN-fold, cross-stage prefetch that wraps to next tile's s0).
__global__ __launch_bounds__(256, 2) void conv_main(
    const u16* __restrict__ xt, const u16* __restrict__ wt,
    const float* __restrict__ shift,
    const float* __restrict__ wexp, float* __restrict__ out,
    u32* __restrict__ ctrs) {
    extern __shared__ char smem[];
    u16* xls = (u16*)smem;                       // [cg 8][P @342] octets
    u16* wls = (u16*)(smem + XLS_BYTES);         // [pos*4+cio 36][co 64] octets
    float* shls = (float*)(smem + XLS_BYTES + WLS_BYTES);   // [4][64] f32
    int* stl = (int*)(smem + XLS_BYTES + WLS_BYTES + SHLS_BYTES);

    const int tid = threadIdx.x;
    const int lane = tid & 63;
    const int wv = tid >> 6;
    const int l31 = lane & 31, kh = lane >> 5;
    const int r0 = 2 * wv;                       // wave's two output rows
    const int xb8 = blockIdx.x & 7;              // XCD proxy (round-robin)

    // issue stage-0 weight DMA first (same data for every tile)
    {
#pragma unroll
        for (int r = 0; r < 9; ++r) {
            int oo = r * 256 + tid;
            __builtin_amdgcn_global_load_lds(
                (const __attribute__((address_space(1))) void*)(wt + oo * 8),
                (__attribute__((address_space(3))) void*)(wls + oo * 8),
                16, 0, 0);
        }
    }
    shls[tid] = shift[tid];

    // lane-constant address bases (u16 indices)
    const int oA2 = (kh * 64 + l31) << 3;        // + pos*2048 + ks*1024 + m2*256
    const int oBk0 = ((kh * XSTRIDE) + r0 * 34 + l31) << 3;          // ks=0
    const int oBk1 = oBk0 + ((2 * XSTRIDE) << 3);                    // ks=1

    for (;;) {
        // ---- steal a tile (block-uniform via LDS broadcast) ----
        if (tid == 0) {
            int got = -1;
            for (int d = 0; d < 8; ++d) {
                int xx = (xb8 + d) & 7;
                u32 tl = atomicAdd(&ctrs[xx], 1u);
                if (tl < 200u) { got = xx * 200 + (int)tl; break; }
            }
            *stl = got;
        }
        __syncthreads();
        const int blk = *stl;
        if (blk < 0) break;

        const int wt5 = blk % 5;
        const int tmp = blk / 5;
        const int ht = tmp % 20;
        const int b = tmp / 20;
        const int h0 = ht * 8, w0 = wt5 * 32;

        const float we0 = wexp[(b << 2) + 0];
        const float we1 = wexp[(b << 2) + 1];
        const float we2 = wexp[(b << 2) + 2];
        const float we3 = wexp[(b << 2) + 3];

        // stage x halo tile (rows h0..h0+9, cols w0..w0+33) into [cg][P@342]
        // (previous tile's last xls read was before the s7 stage-end barrier)
        {
            const u16* xb = xt + (long)b * HP * WPD * 64;
            for (int c = tid; c < 2720; c += 256) {
                int P = c >> 3, cg = c & 7;
                int y = P / 34, px = P - y * 34;
                const u16* src = xb + (((long)(h0 + y) * WPD) + (w0 + px)) * 64 + cg * 8;
                s16x8 v = *(const s16x8*)src;
                *(s16x8*)(&xls[(cg * XSTRIDE + P) << 3]) = v;
            }
        }

        f32x16 acc00 = (f32x16)(0.f), acc01 = (f32x16)(0.f);
        f32x16 acc10 = (f32x16)(0.f), acc11 = (f32x16)(0.f);
        f32x16 oac00 = (f32x16)(0.f), oac01 = (f32x16)(0.f);
        f32x16 oac10 = (f32x16)(0.f), oac11 = (f32x16)(0.f);

        auto epi = [&](int E) {
            const float we = (E == 0) ? we0 : (E == 1) ? we1 : (E == 2) ? we2 : we3;
            const float* shE = shls + (E << 6);
#pragma unroll
            for (int j = 0; j < 16; ++j) {
                const int cob = (j & 3) + 8 * (j >> 2) + 4 * kh;
                {
                    float sh = shE[cob];
                    float y0 = acc00[j] + sh;
                    float y1 = acc01[j] + sh;
                    oac00[j] += we * (y0 * __builtin_amdgcn_rcpf(1.f + __expf(-y0)));
                    oac01[j] += we * (y1 * __builtin_amdgcn_rcpf(1.f + __expf(-y1)));
                }
                {
                    float sh = shE[cob + 32];
                    float y0 = acc10[j] + sh;
                    float y1 = acc11[j] + sh;
                    oac10[j] += we * (y0 * __builtin_amdgcn_rcpf(1.f + __expf(-y0)));
                    oac11[j] += we * (y1 * __builtin_amdgcn_rcpf(1.f + __expf(-y1)));
                }
            }
            acc00 = (f32x16)(0.f); acc01 = (f32x16)(0.f);
            acc10 = (f32x16)(0.f); acc11 = (f32x16)(0.f);
        };

#pragma unroll 1
        for (int s = 0; s < 8; ++s) {
            const int ch = s & 1;
            const int chU = (ch * 4 * XSTRIDE) << 3;
            const int b0U = oBk0 + chU;
            const int b1U = oBk1 + chU;
            const int sn = (s + 1) & 7;          // next stage (wraps to next tile)

            auto dx_group = [&](int g, int pos0) {
                const int gU = g << 3;
                s16x8 B00 = *(const s16x8*)(&xls[b0U + gU]);
                s16x8 B01 = *(const s16x8*)(&xls[b1U + gU]);
                s16x8 B10 = *(const s16x8*)(&xls[b0U + gU + (34 << 3)]);
                s16x8 B11 = *(const s16x8*)(&xls[b1U + gU + (34 << 3)]);
                s16x8 B20 = *(const s16x8*)(&xls[b0U + gU + (68 << 3)]);
                s16x8 B21 = *(const s16x8*)(&xls[b1U + gU + (68 << 3)]);
                s16x8 B30 = *(const s16x8*)(&xls[b0U + gU + (102 << 3)]);
                s16x8 B31 = *(const s16x8*)(&xls[b1U + gU + (102 << 3)]);
                __builtin_amdgcn_s_setprio(1);
#pragma unroll
                for (int dy = 0; dy < 3; ++dy) {
                    const int atU = oA2 + (pos0 + dy) * 2048;
                    s16x8 a00 = *(const s16x8*)(&wls[atU]);
                    s16x8 a10 = *(const s16x8*)(&wls[atU + 256]);
                    s16x8 a01 = *(const s16x8*)(&wls[atU + 1024]);
                    s16x8 a11 = *(const s16x8*)(&wls[atU + 1280]);
                    s16x8 bn00 = (dy == 0) ? B00 : (dy == 1) ? B10 : B20;
                    s16x8 bn01 = (dy == 0) ? B01 : (dy == 1) ? B11 : B21;
                    s16x8 bn10 = (dy == 0) ? B10 : (dy == 1) ? B20 : B30;
                    s16x8 bn11 = (dy == 0) ? B11 : (dy == 1) ? B21 : B31;
                    acc00 = __builtin_amdgcn_mfma_f32_32x32x16_bf16(a00, bn00, acc00, 0, 0, 0);
                    acc10 = __builtin_amdgcn_mfma_f32_32x32x16_bf16(a10, bn00, acc10, 0, 0, 0);
                    acc01 = __builtin_amdgcn_mfma_f32_32x32x16_bf16(a00, bn10, acc01, 0, 0, 0);
                    acc11 = __builtin_amdgcn_mfma_f32_32x32x16_bf16(a10, bn10, acc11, 0, 0, 0);
                    acc00 = __builtin_amdgcn_mfma_f32_32x32x16_bf16(a01, bn01, acc00, 0, 0, 0);
                    acc10 = __builtin_amdgcn_mfma_f32_32x32x16_bf16(a11, bn01, acc10, 0, 0, 0);
                    acc01 = __builtin_amdgcn_mfma_f32_32x32x16_bf16(a01, bn11, acc01, 0, 0, 0);
                    acc11 = __builtin_amdgcn_mfma_f32_32x32x16_bf16(a11, bn11, acc11, 0, 0, 0);
                }
                __builtin_amdgcn_s_setprio(0);
            };

            // phase A: dx-groups 0,1 (rows 0-23)
            if (s == 0) __builtin_amdgcn_s_waitcnt(0x070);   // vmcnt(0) lgkmcnt(0)
            else        __builtin_amdgcn_s_waitcnt(0xF73);   // vmcnt(3)
            __builtin_amdgcn_s_barrier();
            __builtin_amdgcn_sched_barrier(0);
            dx_group(0, 0);
            dx_group(1, 3);

            // phase B: dx-group 2 (rows 24-35); prefetch next stage rows 0-23
            __builtin_amdgcn_s_waitcnt(0xF70);               // vmcnt(0)
            __builtin_amdgcn_s_barrier();
            __builtin_amdgcn_sched_barrier(0);
            {
                const u16* wsrc = wt + ((long)sn) * 2304 * 8;
#pragma unroll
                for (int r = 0; r < 6; ++r) {
                    int oo = r * 256 + tid;
                    __builtin_amdgcn_global_load_lds(
                        (const __attribute__((address_space(1))) void*)(wsrc + oo * 8),
                        (__attribute__((address_space(3))) void*)(wls + oo * 8),
                        16, 0, 0);
                }
            }
            dx_group(2, 6);
            if (ch == 1) epi(s >> 1);

            __builtin_amdgcn_s_barrier();        // all waves done with rows 24-35
            __builtin_amdgcn_sched_barrier(0);
            {
                const u16* wsrc = wt + ((long)sn) * 2304 * 8;
#pragma unroll
                for (int r = 6; r < 9; ++r) {
                    int oo = r * 256 + tid;
                    __builtin_amdgcn_global_load_lds(
                        (const __attribute__((address_space(1))) void*)(wsrc + oo * 8),
                        (__attribute__((address_space(3))) void*)(wls + oo * 8),
                        16, 0, 0);
                }
            }
        }

        // store NCHW f32 (128 B segments: 32 px x 2 co per instr)
        const int yy = h0 + r0;
#pragma unroll
        for (int j = 0; j < 16; ++j) {
            const int cob = (j & 3) + 8 * (j >> 2) + 4 * kh;
            out[(((long)(b * 64 + cob)) * 160 + yy) * 160 + w0 + l31] = oac00[j];
            out[(((long)(b * 64 + cob)) * 160 + yy + 1) * 160 + w0 + l31] = oac01[j];
            out[(((long)(b * 64 + cob + 32)) * 160 + yy) * 160 + w0 + l31] = oac10[j];
            out[(((long)(b * 64 + cob + 32)) * 160 + yy + 1) * 160 + w0 + l31] = oac11[j];
        }
    }
    // drain any in-flight LDS-DMA before the block (and its LDS) retires
    __builtin_amdgcn_s_waitcnt(0xF70);
}

extern "C" void kernel_launch(void* const* d_in, const int* in_sizes, int n_in,
                              void* d_out, int out_size, void* d_ws, size_t ws_size,
                              hipStream_t stream) {
    const float* x = (const float*)d_in[0];
    const float* fc1w = (const float*)d_in[1];
    const float* fc2w = (const float*)d_in[2];
    const float* fc2b = (const float*)d_in[3];
    const float* convw = (const float*)d_in[4];
    const float* gamma = (const float*)d_in[5];
    const float* beta = (const float*)d_in[6];
    const float* mean = (const float*)d_in[7];
    const float* var = (const float*)d_in[8];
    float* out = (float*)d_out;
    char* ws = (char*)d_ws;
    u16* xt = (u16*)(ws + OFF_XT);
    u16* wtb = (u16*)(ws + OFF_WT);
    float* shift = (float*)(ws + OFF_SH);
    float* g = (float*)(ws + OFF_G);
    float* wexp = (float*)(ws + OFF_WE);
    u32* ctrs = (u32*)(ws + OFF_CT);
    float* gpart = (float*)(ws + OFF_GP);

    hipFuncSetAttribute((const void*)conv_main,
                        hipFuncAttributeMaxDynamicSharedMemorySize, SMEM_TOTAL);

    hipMemsetAsync(ctrs, 0, 32, stream);   // reset steal counters every launch
    prep_w<<<576, 256, 0, stream>>>(convw, wtb, gamma, beta, mean, var, shift);
    prep_x<<<15392, 256, 0, stream>>>(x, xt, gpart);
    g_reduce<<<1024, 256, 0, stream>>>(gpart, g);
    router<<<1, 256, 0, stream>>>(g, fc1w, fc2w, fc2b, wexp);
    conv_main<<<512, 256, SMEM_TOTAL, stream>>>(xt, wtb, shift, wexp, out, ctrs);
}

// Round 14
// 180.116 us; speedup vs baseline: 1.3419x; 1.3419x over previous
//
#include <hip/hip_runtime.h>
#include <hip/hip_bf16.h>

typedef unsigned short u16;
typedef unsigned int   u32;
typedef __attribute__((ext_vector_type(8))) short s16x8;
typedef __attribute__((ext_vector_type(16))) float f32x16;

#define BN_EPS 1e-3f
// problem dims
#define NB 16
#define NC 64
#define NH 160
#define NW 160
#define HP 162   // padded H
#define WPD 162  // padded W

// workspace layout (bytes)
#define OFF_XT 0UL
#define SZ_XT  (16UL*162*162*64*2)     // 53,747,712  padded NHWC bf16
#define OFF_WT (OFF_XT + SZ_XT)
#define SZ_WT  (4UL*64*9*64*2)         // 294,912  [e][ch][ks][pos][kh][co][8ci] bf16
#define OFF_SH (OFF_WT + SZ_WT)        // bn shift [4][64] f32
#define OFF_G  (OFF_SH + 1024UL)       // g [16][64] f32
#define OFF_WE (OFF_G + 4096UL)        // wexp [16][4] f32
#define OFF_GP (OFF_WE + 256UL)        // gpart [1024][800] f32 (3.28 MB)

// conv_main LDS partition (dynamic, 81,664 B total -> 2 blocks/CU)
#define XSTRIDE 342
#define XLS_BYTES (8 * XSTRIDE * 16)   // 43,776
#define WLS_BYTES (2 * 1152 * 16)      // 36,864 = 2 buffers x 18 rows x 64 co x 16 B
#define SHLS_BYTES 1024                // shift [4][64] f32 in LDS
#define SMEM_TOTAL (XLS_BYTES + WLS_BYTES + SHLS_BYTES)

__device__ __forceinline__ u16 f2bf(float f) {
    u32 u = __builtin_bit_cast(u32, f);
    u += 0x7fffu + ((u >> 16) & 1u);   // round-to-nearest-even
    return (u16)(u >> 16);
}

// ---- weights -> [stage s=e*4+ch*2+ks][pos][kh][co][8ci] bf16 --------------
// stage panel = one linear 18,432 B chunk; pos stores tap (p%3)*3+(p/3)
// (dx-major); BN scale folded in: w' = w * gamma*rsqrt(var+eps).
__global__ void prep_w(const float* __restrict__ cw, u16* __restrict__ wt,
                       const float* __restrict__ gamma, const float* __restrict__ beta,
                       const float* __restrict__ mean, const float* __restrict__ var,
                       float* __restrict__ shift) {
    int idx = blockIdx.x * 256 + threadIdx.x;
    if (idx < 16 * 9 * 2 * 64 * 8) {
        int cin = idx & 7;
        int o = idx >> 3;
        int co = o & 63; o >>= 6;
        int kh = o & 1;  o >>= 1;
        int pos = o % 9; o /= 9;
        int s = o;                       // stage 0..15
        int ks = s & 1, ch = (s >> 1) & 1, e = s >> 2;
        int tsp = (pos % 3) * 3 + (pos / 3);   // spatial tap dy*3+dx
        int ci = ch * 32 + ks * 16 + kh * 8 + cin;
        int ec = e * 64 + co;
        float sc = gamma[ec] * rsqrtf(var[ec] + BN_EPS);
        wt[idx] = f2bf(cw[(((long)ec) * 64 + ci) * 9 + tsp] * sc);
    }
    if (idx < 256) {
        float sc = gamma[idx] * rsqrtf(var[idx] + BN_EPS);
        shift[idx] = beta[idx] - mean[idx] * sc;
    }
}

// ---- x NCHW f32 -> padded NHWC bf16 + router partials + border zero ------
__global__ void prep_x(const float* __restrict__ x, u16* __restrict__ xt,
                       float* __restrict__ gpart) {
    __shared__ float tile[64][33];
    int blk = blockIdx.x;
    int t = threadIdx.x;
    if (blk >= 12800) {                // zero the 1-px halo border
        int bb = blk - 12800;          // 0..2591 = b*162 + hp
        int hp = bb % 162, b = bb / 162;
        u32* row = (u32*)xt + (((long)b * 162 + hp) * 162) * 32;
        if (hp == 0 || hp == 161) {
            for (int i = t; i < 162 * 32; i += 256) row[i] = 0u;
        } else if (t < 64) {
            int p = (t >> 5) ? 161 : 0;
            row[p * 32 + (t & 31)] = 0u;
        }
        return;
    }
    int wt5 = blk % 5;
    int tmp = blk / 5;
    int h = tmp % 160, b = tmp / 160;
    int w0 = wt5 * 32;
    int w = t & 31, c0 = t >> 5;       // c0 in 0..7
#pragma unroll
    for (int i = 0; i < 8; ++i) {
        int c = c0 + 8 * i;
        tile[c][w] = x[(((long)b * 64 + c) * 160 + h) * 160 + w0 + w];
    }
    __syncthreads();
    if (t < 64) {                      // per-channel partial sum over 32 w
        float s = 0.f;
#pragma unroll
        for (int wi = 0; wi < 32; ++wi) s += tile[t][wi];
        gpart[((long)(b * 64 + t)) * 800 + h * 5 + wt5] = s;
    }
    u32* xt32 = (u32*)xt;
    long base = ((((long)b * 162 + h + 1) * 162) + (w0 + 1)) * 32; // u32 index
#pragma unroll
    for (int j = 0; j < 4; ++j) {
        int idx = t + 256 * j;         // 0..1023
        int p = idx >> 5, cp = idx & 31;
        float v0 = tile[2 * cp][p], v1 = tile[2 * cp + 1][p];
        xt32[base + p * 32 + cp] = (u32)f2bf(v0) | ((u32)f2bf(v1) << 16);
    }
}

// ---- finish global average pool (1024 blocks: parallel) ------------------
__global__ void g_reduce(const float* __restrict__ gpart, float* __restrict__ g) {
    int id = blockIdx.x;               // 1024 = b*64+c
    int t = threadIdx.x;
    float s = 0.f;
    for (int i = t; i < 800; i += 256) s += gpart[(long)id * 800 + i];
#pragma unroll
    for (int off = 32; off > 0; off >>= 1) s += __shfl_down(s, off, 64);
    __shared__ float red[4];
    if ((t & 63) == 0) red[t >> 6] = s;
    __syncthreads();
    if (t == 0) g[id] = (red[0] + red[1] + red[2] + red[3]) * (1.f / 25600.f);
}

// ---- router: fc1 -> relu -> fc2 -> softmax -------------------------------
__global__ void router(const float* __restrict__ g, const float* __restrict__ fc1w,
                       const float* __restrict__ fc2w, const float* __restrict__ fc2b,
                       float* __restrict__ wexp) {
    __shared__ float gL[16][64];
    __shared__ float h1[16][16];
    __shared__ float z[16][4];
    int t = threadIdx.x;
    for (int i = t; i < 1024; i += 256) gL[i >> 6][i & 63] = g[i];
    __syncthreads();
    {
        int b = t >> 4, r = t & 15;
        float s = 0.f;
#pragma unroll
        for (int c = 0; c < 64; ++c) s += gL[b][c] * fc1w[r * 64 + c];
        h1[b][r] = fmaxf(s, 0.f);
    }
    __syncthreads();
    if (t < 64) {
        int b = t >> 2, e = t & 3;
        float s = fc2b[e];
#pragma unroll
        for (int r = 0; r < 16; ++r) s += h1[b][r] * fc2w[e * 16 + r];
        z[b][e] = s;
    }
    __syncthreads();
    if (t < 16) {
        int b = t;
        float m = fmaxf(fmaxf(z[b][0], z[b][1]), fmaxf(z[b][2], z[b][3]));
        float e0 = __expf(z[b][0] - m), e1 = __expf(z[b][1] - m);
        float e2 = __expf(z[b][2] - m), e3 = __expf(z[b][3] - m);
        float inv = 1.f / (e0 + e1 + e2 + e3);
        wexp[b * 4 + 0] = e0 * inv; wexp[b * 4 + 1] = e1 * inv;
        wexp[b * 4 + 2] = e2 * inv; wexp[b * 4 + 3] = e3 * inv;
    }
}

// ---- main: 4-expert implicit-GEMM conv + BN + SiLU + weighted sum --------
// grid 1600 (static, XCD-swizzled); block 256 (4 waves); wave tile 64co x
// 64px via 32x32x16 MFMA. DOUBLE-BUFFERED weight pipeline: 16 stages of
// (e,ch,ks), 18 k-rows (18,432 B) each, ping-pong buffers. Per stage:
// vmcnt(0) [drains DMA issued one stage earlier] -> ONE barrier -> issue
// next stage's DMA into the other buffer -> 36 MFMA. Epilogue VMEM-free.
__global__ __launch_bounds__(256, 2) void conv_main(
    const u16* __restrict__ xt, const u16* __restrict__ wt,
    const float* __restrict__ shift,
    const float* __restrict__ wexp, float* __restrict__ out) {
    extern __shared__ char smem[];
    u16* xls = (u16*)smem;                       // [cg 8][P @342] octets
    u16* wls = (u16*)(smem + XLS_BYTES);         // 2 x [18 rows][64 co] octets
    float* shls = (float*)(smem + XLS_BYTES + WLS_BYTES);   // [4][64] f32

    // bijective chunked XCD swizzle (1600 % 8 == 0)
    const int o = blockIdx.x;
    const int blk = (o & 7) * 200 + (o >> 3);
    const int wt5 = blk % 5;
    const int tmp = blk / 5;
    const int ht = tmp % 20;
    const int b = tmp / 20;
    const int h0 = ht * 8, w0 = wt5 * 32;
    const int tid = threadIdx.x;
    const int lane = tid & 63;
    const int wv = tid >> 6;
    const int l31 = lane & 31, kh = lane >> 5;
    const int r0 = 2 * wv;                       // wave's two output rows

    // issue stage-0 weight DMA first (buffer 0): 6 rounds x 192 threads
    if (tid < 192) {
#pragma unroll
        for (int r = 0; r < 6; ++r) {
            int oo = r * 192 + tid;
            __builtin_amdgcn_global_load_lds(
                (const __attribute__((address_space(1))) void*)(wt + oo * 8),
                (__attribute__((address_space(3))) void*)(wls + oo * 8),
                16, 0, 0);
        }
    }
    // preload router weights (4 regs) + shift into LDS (1 KB)
    const float we0 = wexp[(b << 2) + 0];
    const float we1 = wexp[(b << 2) + 1];
    const float we2 = wexp[(b << 2) + 2];
    const float we3 = wexp[(b << 2) + 3];
    shls[tid] = shift[tid];
    // stage x halo tile (rows h0..h0+9, cols w0..w0+33) into [cg][P@342]
    {
        const u16* xb = xt + (long)b * HP * WPD * 64;
        for (int c = tid; c < 2720; c += 256) {
            int P = c >> 3, cg = c & 7;
            int y = P / 34, px = P - y * 34;
            const u16* src = xb + (((long)(h0 + y) * WPD) + (w0 + px)) * 64 + cg * 8;
            s16x8 v = *(const s16x8*)src;
            *(s16x8*)(&xls[(cg * XSTRIDE + P) << 3]) = v;
        }
    }

    f32x16 acc00 = (f32x16)(0.f), acc01 = (f32x16)(0.f);
    f32x16 acc10 = (f32x16)(0.f), acc11 = (f32x16)(0.f);
    f32x16 oac00 = (f32x16)(0.f), oac01 = (f32x16)(0.f);
    f32x16 oac10 = (f32x16)(0.f), oac11 = (f32x16)(0.f);

    auto epi = [&](int E) {
        const float we = (E == 0) ? we0 : (E == 1) ? we1 : (E == 2) ? we2 : we3;
        const float* shE = shls + (E << 6);      // LDS broadcast reads
#pragma unroll
        for (int j = 0; j < 16; ++j) {
            const int cob = (j & 3) + 8 * (j >> 2) + 4 * kh;
            {
                float sh = shE[cob];
                float y0 = acc00[j] + sh;
                float y1 = acc01[j] + sh;
                oac00[j] += we * (y0 * __builtin_amdgcn_rcpf(1.f + __expf(-y0)));
                oac01[j] += we * (y1 * __builtin_amdgcn_rcpf(1.f + __expf(-y1)));
            }
            {
                float sh = shE[cob + 32];
                float y0 = acc10[j] + sh;
                float y1 = acc11[j] + sh;
                oac10[j] += we * (y0 * __builtin_amdgcn_rcpf(1.f + __expf(-y0)));
                oac11[j] += we * (y1 * __builtin_amdgcn_rcpf(1.f + __expf(-y1)));
            }
        }
        acc00 = (f32x16)(0.f); acc01 = (f32x16)(0.f);
        acc10 = (f32x16)(0.f); acc11 = (f32x16)(0.f);
    };

#pragma unroll 1
    for (int s = 0; s < 16; ++s) {
        const int ks = s & 1, ch = (s >> 1) & 1;
        const int wbU = (s & 1) * 9216;          // this stage's buffer (u16 idx)

        // drain THIS stage's DMA (issued one full stage ago), then sync.
        if (s == 0) __builtin_amdgcn_s_waitcnt(0x070);   // vmcnt(0) lgkmcnt(0)
        else        __builtin_amdgcn_s_waitcnt(0xF70);   // vmcnt(0)
        __builtin_amdgcn_s_barrier();
        __builtin_amdgcn_sched_barrier(0);

        // prefetch next stage into the OTHER buffer (safe: the barrier
        // proves all waves finished reading it in stage s-1)
        if (s < 15 && tid < 192) {
            const u16* wsrc = wt + (long)(s + 1) * 9216;
            const int dbU = ((s + 1) & 1) * 9216;
#pragma unroll
            for (int r = 0; r < 6; ++r) {
                int oo = r * 192 + tid;
                __builtin_amdgcn_global_load_lds(
                    (const __attribute__((address_space(1))) void*)(wsrc + oo * 8),
                    (__attribute__((address_space(3))) void*)(wls + dbU + oo * 8),
                    16, 0, 0);
            }
        }

        // B base for this stage: cg = ch*4 + ks*2 + kh
        const int bU = (((ch * 4 + ks * 2 + kh) * XSTRIDE) + r0 * 34 + l31) << 3;

        auto dx_group = [&](int g, int pos0) {
            const int gU = g << 3;               // dx offset (u16 units)
            s16x8 B0 = *(const s16x8*)(&xls[bU + gU]);
            s16x8 B1 = *(const s16x8*)(&xls[bU + gU + (34 << 3)]);
            s16x8 B2 = *(const s16x8*)(&xls[bU + gU + (68 << 3)]);
            s16x8 B3 = *(const s16x8*)(&xls[bU + gU + (102 << 3)]);
            __builtin_amdgcn_s_setprio(1);
#pragma unroll
            for (int dy = 0; dy < 3; ++dy) {
                const int atU = wbU + ((((pos0 + dy) * 2 + kh) * 64 + l31) << 3);
                s16x8 a0 = *(const s16x8*)(&wls[atU]);           // co 0-31
                s16x8 a1 = *(const s16x8*)(&wls[atU + 256]);     // co 32-63
                s16x8 bn0 = (dy == 0) ? B0 : (dy == 1) ? B1 : B2; // row r0+dy
                s16x8 bn1 = (dy == 0) ? B1 : (dy == 1) ? B2 : B3; // row r0+1+dy
                acc00 = __builtin_amdgcn_mfma_f32_32x32x16_bf16(a0, bn0, acc00, 0, 0, 0);
                acc10 = __builtin_amdgcn_mfma_f32_32x32x16_bf16(a1, bn0, acc10, 0, 0, 0);
                acc01 = __builtin_amdgcn_mfma_f32_32x32x16_bf16(a0, bn1, acc01, 0, 0, 0);
                acc11 = __builtin_amdgcn_mfma_f32_32x32x16_bf16(a1, bn1, acc11, 0, 0, 0);
            }
            __builtin_amdgcn_s_setprio(0);
        };

        dx_group(0, 0);
        dx_group(1, 3);
        dx_group(2, 6);

        if ((s & 3) == 3) epi(s >> 2);           // expert complete (pure VALU)
    }

    // store NCHW f32: per instr 32 consecutive px x 2 co (128 B segments)
    const int yy = h0 + r0;
#pragma unroll
    for (int j = 0; j < 16; ++j) {
        const int cob = (j & 3) + 8 * (j >> 2) + 4 * kh;
        out[(((long)(b * 64 + cob)) * 160 + yy) * 160 + w0 + l31] = oac00[j];
        out[(((long)(b * 64 + cob)) * 160 + yy + 1) * 160 + w0 + l31] = oac01[j];
        out[(((long)(b * 64 + cob + 32)) * 160 + yy) * 160 + w0 + l31] = oac10[j];
        out[(((long)(b * 64 + cob + 32)) * 160 + yy + 1) * 160 + w0 + l31] = oac11[j];
    }
}

extern "C" void kernel_launch(void* const* d_in, const int* in_sizes, int n_in,
                              void* d_out, int out_size, void* d_ws, size_t ws_size,
                              hipStream_t stream) {
    const float* x = (const float*)d_in[0];
    const float* fc1w = (const float*)d_in[1];
    const float* fc2w = (const float*)d_in[2];
    const float* fc2b = (const float*)d_in[3];
    const float* convw = (const float*)d_in[4];
    const float* gamma = (const float*)d_in[5];
    const float* beta = (const float*)d_in[6];
    const float* mean = (const float*)d_in[7];
    const float* var = (const float*)d_in[8];
    float* out = (float*)d_out;
    char* ws = (char*)d_ws;
    u16* xt = (u16*)(ws + OFF_XT);
    u16* wtb = (u16*)(ws + OFF_WT);
    float* shift = (float*)(ws + OFF_SH);
    float* g = (float*)(ws + OFF_G);
    float* wexp = (float*)(ws + OFF_WE);
    float* gpart = (float*)(ws + OFF_GP);

    hipFuncSetAttribute((const void*)conv_main,
                        hipFuncAttributeMaxDynamicSharedMemorySize, SMEM_TOTAL);

    prep_w<<<576, 256, 0, stream>>>(convw, wtb, gamma, beta, mean, var, shift);
    prep_x<<<15392, 256, 0, stream>>>(x, xt, gpart);
    g_reduce<<<1024, 256, 0, stream>>>(gpart, g);
    router<<<1, 256, 0, stream>>>(g, fc1w, fc2w, fc2b, wexp);
    conv_main<<<1600, 256, SMEM_TOTAL, stream>>>(xt, wtb, shift, wexp, out);
}